// Round 13
// baseline (156.003 us; speedup 1.0000x reference)
//
#include <hip/hip_runtime.h>
#include <math.h>

typedef unsigned short u16;
typedef short bf16x8 __attribute__((ext_vector_type(8)));
typedef float f32x4 __attribute__((ext_vector_type(4)));

#define ROPE_SC 0.18033688011112042f   // 0.125 * log2(e)

// ---------- helpers ----------
__device__ __forceinline__ u16 f2bf(float f) {
    union { float f; unsigned u; } x; x.f = f;
    unsigned u = x.u;
    unsigned r = (u + 0x7fffu + ((u >> 16) & 1u)) >> 16;   // RNE, no NaN in data
    return (u16)r;
}
__device__ __forceinline__ unsigned pack2(float a, float b) {
    return (unsigned)f2bf(a) | ((unsigned)f2bf(b) << 16);
}
__device__ __forceinline__ f32x4 mfma16(bf16x8 a, bf16x8 b, f32x4 c) {
    return __builtin_amdgcn_mfma_f32_16x16x32_bf16(a, b, c, 0, 0, 0);
}
__device__ __forceinline__ void gload_lds16(const void* g, void* l) {
    __builtin_amdgcn_global_load_lds((const __attribute__((address_space(1))) void*)g,
                                     (__attribute__((address_space(3))) void*)l,
                                     16, 0, 0);
}

// ---------- fp32 -> bf16 cast (vectorized) ----------
__global__ void cvt_bf16(const float* __restrict__ X, u16* __restrict__ Y) {
    int i = (blockIdx.x * 256 + threadIdx.x) * 4;
    float4 v = *(const float4*)(X + i);
    uint2 o;
    o.x = pack2(v.x, v.y);
    o.y = pack2(v.z, v.w);
    *(uint2*)(Y + i) = o;
}

// ---------- W[R][C] fp32 -> Wt[C][R] bf16 (LDS-tiled transpose) ----------
__global__ void transpose_cvt(const float* __restrict__ W, u16* __restrict__ Wt,
                              int R, int C) {
    __shared__ u16 tile[32][33];
    int tx = threadIdx.x & 31, ty = threadIdx.x >> 5;  // 32 x 8
    int bx = blockIdx.x * 32;
    int by = blockIdx.y * 32;
#pragma unroll
    for (int r = ty; r < 32; r += 8)
        tile[r][tx] = f2bf(W[(size_t)(by + r) * C + bx + tx]);
    __syncthreads();
#pragma unroll
    for (int r = ty; r < 32; r += 8)
        Wt[(size_t)(bx + r) * R + by + tx] = tile[tx][r];
}

// ---------- sin/cos table: tab[0..65535]=cos(t,d), tab[65536..]=sin ----------
__global__ void rope_tab(float* __restrict__ tab) {
    int i = blockIdx.x * 256 + threadIdx.x;   // 65536 = 2048 t x 32 d
    int t = i >> 5, d = i & 31;
    float invf = powf(10000.0f, -(float)d / 32.0f);
    float ang = (float)t * invf;
    tab[i] = cosf(ang);
    tab[i + 65536] = sinf(ang);
}

// ---------- fused QKV GEMM + RoPE + pack epilogue, 8 waves (512 thr) ----------
__global__ __launch_bounds__(512) void gemm_qkv(const u16* __restrict__ A,
                                                const u16* __restrict__ Bt,
                                                const float* __restrict__ tab,
                                                u16* __restrict__ qb,
                                                u16* __restrict__ kb,
                                                u16* __restrict__ vt,
                                                int M, int N, int K) {
    __shared__ u16 lA[128 * 64];
    __shared__ u16 lB[128 * 64];
    const int tid = threadIdx.x;
    const int wave = tid >> 6, lane = tid & 63;
    const int l15 = lane & 15, l4 = lane >> 4;
    const int nwg = gridDim.x * gridDim.y;
    const int orig = blockIdx.y * gridDim.x + blockIdx.x;
    const int swz = (orig & 7) * (nwg >> 3) + (orig >> 3);
    const int m0 = (swz / gridDim.x) * 128, n0 = (swz % gridDim.x) * 128;
    const int wm = (wave >> 1) * 32, wn = (wave & 1) * 64;
    f32x4 acc[2][4] = {};
    for (int k0 = 0; k0 < K; k0 += 64) {
#pragma unroll
        for (int it = 0; it < 2; ++it) {
            int cb = it * 512 + wave * 64;
            int c = cb + lane;
            int r = c >> 3, s = c & 7;
            int sd = ((s ^ (r & 7)) << 3);
            gload_lds16(A + (size_t)(m0 + r) * K + k0 + sd, &lA[(size_t)cb * 8]);
            gload_lds16(Bt + (size_t)(n0 + r) * K + k0 + sd, &lB[(size_t)cb * 8]);
        }
        __syncthreads();
#pragma unroll
        for (int kk = 0; kk < 2; ++kk) {
            bf16x8 af[2], bf[4];
#pragma unroll
            for (int mi = 0; mi < 2; ++mi) {
                int row = wm + mi * 16 + l15;
                af[mi] = *(const bf16x8*)(&lA[row * 64 + (((kk * 4 + l4) ^ (row & 7)) << 3)]);
            }
#pragma unroll
            for (int ni = 0; ni < 4; ++ni) {
                int row = wn + ni * 16 + l15;
                bf[ni] = *(const bf16x8*)(&lB[row * 64 + (((kk * 4 + l4) ^ (row & 7)) << 3)]);
            }
#pragma unroll
            for (int mi = 0; mi < 2; ++mi)
#pragma unroll
                for (int ni = 0; ni < 4; ++ni)
                    acc[mi][ni] = mfma16(af[mi], bf[ni], acc[mi][ni]);
        }
        __syncthreads();
    }
    // ---- fused epilogue ----
    const int colg = n0 + wn;
    const int region = colg >> 10;       // 0=q, 1=k, 2=v
    const int h = (colg & 1023) >> 6;
    if (region == 2) {
#pragma unroll
        for (int mi = 0; mi < 2; ++mi) {
            int t0 = m0 + wm + mi * 16 + l4 * 4;
            int b = t0 >> 11, tq0 = t0 & 2047;
#pragma unroll
            for (int ni = 0; ni < 4; ++ni) {
                int dcol = ni * 16 + l15;
                uint2 pk;
                pk.x = pack2(acc[mi][ni][0], acc[mi][ni][1]);
                pk.y = pack2(acc[mi][ni][2], acc[mi][ni][3]);
                *(uint2*)(vt + ((size_t)(b * 16 + h) * 64 + dcol) * 2048 + tq0) = pk;
            }
        }
    } else {
        const float sc = (region == 0) ? ROPE_SC : 1.0f;
        u16* dst = (region == 0) ? qb : kb;
#pragma unroll
        for (int mi = 0; mi < 2; ++mi)
#pragma unroll
            for (int i = 0; i < 4; ++i) {
                int t = m0 + wm + mi * 16 + l4 * 4 + i;
                int b = t >> 11, tq = t & 2047;
                const float* tcb = tab + tq * 32;
                const float* tsb = tab + 65536 + tq * 32;
                size_t base = ((size_t)(b * 16 + h) * 2048 + tq) * 64;
#pragma unroll
                for (int ni = 0; ni < 2; ++ni) {
                    int d32 = ni * 16 + l15;
                    float cs = tcb[d32], sn = tsb[d32];
                    float a = acc[mi][ni][i], bb = acc[mi][ni + 2][i];
                    dst[base + d32]      = f2bf((a * cs - bb * sn) * sc);
                    dst[base + d32 + 32] = f2bf((bb * cs + a * sn) * sc);
                }
            }
    }
}

// ---------- GEMM 128x64 tile (final proj), 8 waves: grid (N/64, M/128) ----------
__global__ __launch_bounds__(512) void gemm_bt_n64(const u16* __restrict__ A,
                                                   const u16* __restrict__ Bt,
                                                   float* __restrict__ C,
                                                   int M, int N, int K) {
    __shared__ u16 lA[128 * 64];
    __shared__ u16 lB[64 * 64];
    const int tid = threadIdx.x;
    const int wave = tid >> 6, lane = tid & 63;
    const int l15 = lane & 15, l4 = lane >> 4;
    const int nwg = gridDim.x * gridDim.y;
    const int orig = blockIdx.y * gridDim.x + blockIdx.x;
    const int swz = (orig & 7) * (nwg >> 3) + (orig >> 3);
    const int m0 = (swz / gridDim.x) * 128, n0 = (swz % gridDim.x) * 64;
    const int wm = (wave >> 1) * 32, wn = (wave & 1) * 32;
    f32x4 acc[2][2] = {};
    for (int k0 = 0; k0 < K; k0 += 64) {
#pragma unroll
        for (int it = 0; it < 2; ++it) {
            int cb = it * 512 + wave * 64;
            int c = cb + lane;
            int r = c >> 3, s = c & 7;
            int sd = ((s ^ (r & 7)) << 3);
            gload_lds16(A + (size_t)(m0 + r) * K + k0 + sd, &lA[(size_t)cb * 8]);
        }
        {
            int cb = wave * 64;
            int c = cb + lane;
            int r = c >> 3, s = c & 7;
            int sd = ((s ^ (r & 7)) << 3);
            gload_lds16(Bt + (size_t)(n0 + r) * K + k0 + sd, &lB[(size_t)cb * 8]);
        }
        __syncthreads();
#pragma unroll
        for (int kk = 0; kk < 2; ++kk) {
            bf16x8 af[2], bf[2];
#pragma unroll
            for (int mi = 0; mi < 2; ++mi) {
                int row = wm + mi * 16 + l15;
                af[mi] = *(const bf16x8*)(&lA[row * 64 + (((kk * 4 + l4) ^ (row & 7)) << 3)]);
            }
#pragma unroll
            for (int ni = 0; ni < 2; ++ni) {
                int row = wn + ni * 16 + l15;
                bf[ni] = *(const bf16x8*)(&lB[row * 64 + (((kk * 4 + l4) ^ (row & 7)) << 3)]);
            }
#pragma unroll
            for (int mi = 0; mi < 2; ++mi)
#pragma unroll
                for (int ni = 0; ni < 2; ++ni)
                    acc[mi][ni] = mfma16(af[mi], bf[ni], acc[mi][ni]);
        }
        __syncthreads();
    }
#pragma unroll
    for (int mi = 0; mi < 2; ++mi)
#pragma unroll
        for (int ni = 0; ni < 2; ++ni)
#pragma unroll
            for (int i = 0; i < 4; ++i) {
                int r = m0 + wm + mi * 16 + l4 * 4 + i;
                int cc = n0 + wn + ni * 16 + l15;
                C[(size_t)r * N + cc] = acc[mi][ni][i];
            }
}

// ---------- causal flash attention v13: 2-wave blocks, 32-row q-tiles, ----------
// ---------- K in LDS (dbuf), V read directly from L1/L2 (no staging).  ----------
// grid 2048: xcd=orig&7 owns 4 heads; p=orig>>3: layer=p&3, idx=p>>2 (0..63);
// bh=xcd*4+layer; qt=(layer&1)?idx:63-idx (32-row tile). niter=(qt>>1)+1.
// Per-wave compute verbatim from flash10 (pi-scramble QK, zero-shuffle P->PV).
__global__ __launch_bounds__(128, 8) void flash13(const u16* __restrict__ qb,
                                                  const u16* __restrict__ kb,
                                                  const u16* __restrict__ vt,
                                                  u16* __restrict__ ao) {
    __shared__ u16 lK[2][64 * 64];   // 16 KB: [kv][d], f_K-XOR-swizzled 16B slots
    const int orig = blockIdx.x;
    const int xcd = orig & 7, p = orig >> 3;
    const int layer = p & 3, idx = p >> 2;
    const int bh = xcd * 4 + layer;
    const int qt = (layer & 1) ? idx : 63 - idx;   // 0..63 (32-row tiles)
    const int b = bh >> 4, h = bh & 15;
    const int tid = threadIdx.x;
    const int wave = tid >> 6, lane = tid & 63;
    const int l15 = lane & 15, l4 = lane >> 4;
    const int niter = (qt >> 1) + 1;
    const u16* qptr = qb + (size_t)bh * 2048 * 64;
    const u16* kptr = kb + (size_t)bh * 2048 * 64;
    const u16* vptr = vt + (size_t)bh * 64 * 2048;

    const int qrow = qt * 32 + wave * 16 + l15;
    bf16x8 q0 = *(const bf16x8*)(qptr + (size_t)qrow * 64 + l4 * 8);
    bf16x8 q1 = *(const bf16x8*)(qptr + (size_t)qrow * 64 + 32 + l4 * 8);

    f32x4 O[4] = {};
    float mrun = -INFINITY, lrun = 0.f;

    int idxO[4];
#pragma unroll
    for (int i = 0; i < 4; ++i) idxO[i] = (lane & 48) | (l4 * 4 + i);

    const int r0q = ((l15 >> 2) << 3) | (l15 & 3);   // pi base row

    // staging: 128 threads x 4 chunks cover the 512 16B K-chunks
    auto stage = [&](int buf, int kv0) {
#pragma unroll
        for (int it = 0; it < 4; ++it) {
            int cb = it * 128 + wave * 64;       // wave-uniform chunk base
            int c = cb + lane;
            int r = c >> 3, s = c & 7;
            int fK = (r & 3) | ((r >> 1) & 4);
            gload_lds16(kptr + (size_t)(kv0 + r) * 64 + ((s ^ fK) << 3), &lK[buf][cb * 8]);
        }
    };
    auto ldK = [&](int buf, int row, int slot) -> bf16x8 {
        int f = (row & 3) | ((row >> 1) & 4);
        return *(const bf16x8*)(&lK[buf][row * 64 + ((slot ^ f) << 3)]);
    };
    auto ldVg = [&](int kv0, int row, int slot) -> bf16x8 {
        return *(const bf16x8*)(vptr + (size_t)row * 2048 + kv0 + slot * 8);
    };

    // softmax + pack-to-A-frag; p[m][i] at kv = kv0 + 32(m>>1) + 8*l4 + 4(m&1) + i
    auto smpack = [&](f32x4 S[4], float& mr, float& lr, f32x4 Ov[4],
                      bf16x8 af[2], bool diag, int kv0, int qr) {
        float p2[4][4];
#pragma unroll
        for (int m = 0; m < 4; ++m)
#pragma unroll
            for (int i = 0; i < 4; ++i) {
                float s = S[m][i];
                if (diag && (kv0 + ((m >> 1) << 5) + (l4 << 3) + ((m & 1) << 2) + i > qr))
                    s = -INFINITY;
                p2[m][i] = s;
            }
        float m = p2[0][0];
#pragma unroll
        for (int c = 0; c < 4; ++c)
#pragma unroll
            for (int i = 0; i < 4; ++i) m = fmaxf(m, p2[c][i]);
        m = fmaxf(m, __shfl_xor(m, 16));
        m = fmaxf(m, __shfl_xor(m, 32));
        float mnew = fmaxf(mr, m);
        float corr = __builtin_amdgcn_exp2f(mr - mnew);
        float rs = 0.f;
#pragma unroll
        for (int c = 0; c < 4; ++c)
#pragma unroll
            for (int i = 0; i < 4; ++i) { p2[c][i] = __builtin_amdgcn_exp2f(p2[c][i] - mnew); rs += p2[c][i]; }
        rs += __shfl_xor(rs, 16);
        rs += __shfl_xor(rs, 32);
        lr = lr * corr + rs;
        mr = mnew;
#pragma unroll
        for (int i = 0; i < 4; ++i) {
            float cf = __shfl(corr, idxO[i]);
#pragma unroll
            for (int c2 = 0; c2 < 4; ++c2) Ov[c2][i] *= cf;
        }
        unsigned w[4][2];
#pragma unroll
        for (int c = 0; c < 4; ++c) {
            asm("v_cvt_pk_bf16_f32 %0, %1, %2" : "=v"(w[c][0]) : "v"(p2[c][0]), "v"(p2[c][1]));
            asm("v_cvt_pk_bf16_f32 %0, %1, %2" : "=v"(w[c][1]) : "v"(p2[c][2]), "v"(p2[c][3]));
        }
#pragma unroll
        for (int ks = 0; ks < 2; ++ks) {
            union { unsigned u[4]; bf16x8 v; } cvt;
            cvt.u[0] = w[2 * ks][0];
            cvt.u[1] = w[2 * ks][1];
            cvt.u[2] = w[2 * ks + 1][0];
            cvt.u[3] = w[2 * ks + 1][1];
            af[ks] = cvt.v;
        }
    };

    stage(0, 0);
    for (int kvb = 0; kvb < niter; ++kvb) {
        const int cur = kvb & 1;
        const int kv0 = kvb * 64;
        if (kvb < niter - 1) {
            stage(cur ^ 1, kv0 + 64);
            asm volatile("s_waitcnt vmcnt(4)" ::: "memory");
        } else {
            asm volatile("s_waitcnt vmcnt(0)" ::: "memory");
        }
        __builtin_amdgcn_s_barrier();
        __builtin_amdgcn_sched_barrier(0);

        // QK^T swapped with pi-scrambled A-rows
        f32x4 S[4] = {};
#pragma unroll
        for (int mm = 0; mm < 4; ++mm) {
            int row = r0q + ((mm >> 1) << 5) + ((mm & 1) << 2);
            bf16x8 kf0 = ldK(cur, row, l4);
            bf16x8 kf1 = ldK(cur, row, 4 + l4);
            S[mm] = mfma16(kf0, q0, S[mm]);
            S[mm] = mfma16(kf1, q1, S[mm]);
        }
        bf16x8 af[2];
        smpack(S, mrun, lrun, O, af, kvb == niter - 1, kv0, qrow);
#pragma unroll
        for (int ks = 0; ks < 2; ++ks)
#pragma unroll
            for (int c2 = 0; c2 < 4; ++c2) {
                bf16x8 vf = ldVg(kv0, c2 * 16 + l15, ks * 4 + l4);
                O[c2] = mfma16(af[ks], vf, O[c2]);
            }
        __builtin_amdgcn_s_barrier();   // protect K buffer overwrite by next stage
    }

    // epilogue: O rows are q'=l4*4+i, cols d=c2*16+l15
#pragma unroll
    for (int i = 0; i < 4; ++i) {
        float lv = __shfl(lrun, idxO[i]);
        float rcp = 1.f / lv;
        int qg = qt * 32 + wave * 16 + l4 * 4 + i;
#pragma unroll
        for (int c2 = 0; c2 < 4; ++c2)
            ao[(size_t)(b * 2048 + qg) * 1024 + h * 64 + c2 * 16 + l15] = f2bf(O[c2][i] * rcp);
    }
}

// ---------- launch ----------
extern "C" void kernel_launch(void* const* d_in, const int* in_sizes, int n_in,
                              void* d_out, int out_size, void* d_ws, size_t ws_size,
                              hipStream_t stream) {
    const float* x    = (const float*)d_in[0];   // (2,2048,1024)
    const float* Wqkv = (const float*)d_in[1];   // (1024,3072)
    const float* Wout = (const float*)d_in[2];   // (1024,1024)
    float* out = (float*)d_out;                  // (2,2048,1024)
    char* ws = (char*)d_ws;

    u16*   xb  = (u16*)(ws + 0);            // 8 MB  (4096x1024 bf16)
    u16*   Wtq = (u16*)(ws + 8388608);      // 6 MB  (3072x1024 bf16)
    u16*   Wto = (u16*)(ws + 14680064);     // 2 MB  (1024x1024 bf16)
    u16*   qb  = (u16*)(ws + 67108864);     // 8 MB  (B,H,T,Dh bf16, pre-scaled)
    u16*   kb  = (u16*)(ws + 75497472);     // 8 MB
    u16*   vt  = (u16*)(ws + 83886080);     // 8 MB  (B,H,Dh,T bf16)
    float* tab = (float*)(ws + 92274688);   // 512 KB sin/cos table
    u16*   ao  = (u16*)(ws + 0);            // reuse xb region (gemm_qkv done by then)

    cvt_bf16<<<dim3(4096), dim3(256), 0, stream>>>(x, xb);
    transpose_cvt<<<dim3(96, 32), dim3(256), 0, stream>>>(Wqkv, Wtq, 1024, 3072);
    transpose_cvt<<<dim3(32, 32), dim3(256), 0, stream>>>(Wout, Wto, 1024, 1024);
    rope_tab<<<dim3(256), dim3(256), 0, stream>>>(tab);
    gemm_qkv<<<dim3(24, 32), dim3(512), 0, stream>>>(xb, Wtq, tab, qb, kb, vt, 4096, 3072, 1024);
    flash13<<<dim3(2048), dim3(128), 0, stream>>>(qb, kb, vt, ao);
    gemm_bt_n64<<<dim3(16, 32), dim3(512), 0, stream>>>(ao, Wto, out, 4096, 1024, 1024);
}

// Round 14
// 105.892 us; speedup vs baseline: 1.4732x; 1.4732x over previous
//
#include <hip/hip_runtime.h>
#include <math.h>

typedef unsigned short u16;
typedef short bf16x8 __attribute__((ext_vector_type(8)));
typedef float f32x4 __attribute__((ext_vector_type(4)));

#define ROPE_SC 0.18033688011112042f   // 0.125 * log2(e)

// ---------- helpers ----------
__device__ __forceinline__ u16 f2bf(float f) {
    union { float f; unsigned u; } x; x.f = f;
    unsigned u = x.u;
    unsigned r = (u + 0x7fffu + ((u >> 16) & 1u)) >> 16;   // RNE, no NaN in data
    return (u16)r;
}
__device__ __forceinline__ unsigned pack2(float a, float b) {
    return (unsigned)f2bf(a) | ((unsigned)f2bf(b) << 16);
}
__device__ __forceinline__ f32x4 mfma16(bf16x8 a, bf16x8 b, f32x4 c) {
    return __builtin_amdgcn_mfma_f32_16x16x32_bf16(a, b, c, 0, 0, 0);
}
__device__ __forceinline__ void gload_lds16(const void* g, void* l) {
    __builtin_amdgcn_global_load_lds((const __attribute__((address_space(1))) void*)g,
                                     (__attribute__((address_space(3))) void*)l,
                                     16, 0, 0);
}

// ---------- fp32 -> bf16 cast (vectorized) ----------
__global__ void cvt_bf16(const float* __restrict__ X, u16* __restrict__ Y) {
    int i = (blockIdx.x * 256 + threadIdx.x) * 4;
    float4 v = *(const float4*)(X + i);
    uint2 o;
    o.x = pack2(v.x, v.y);
    o.y = pack2(v.z, v.w);
    *(uint2*)(Y + i) = o;
}

// ---------- W[R][C] fp32 -> Wt[C][R] bf16 (LDS-tiled transpose) ----------
__global__ void transpose_cvt(const float* __restrict__ W, u16* __restrict__ Wt,
                              int R, int C) {
    __shared__ u16 tile[32][33];
    int tx = threadIdx.x & 31, ty = threadIdx.x >> 5;  // 32 x 8
    int bx = blockIdx.x * 32;
    int by = blockIdx.y * 32;
#pragma unroll
    for (int r = ty; r < 32; r += 8)
        tile[r][tx] = f2bf(W[(size_t)(by + r) * C + bx + tx]);
    __syncthreads();
#pragma unroll
    for (int r = ty; r < 32; r += 8)
        Wt[(size_t)(bx + r) * R + by + tx] = tile[tx][r];
}

// ---------- sin/cos table: tab[0..65535]=cos(t,d), tab[65536..]=sin ----------
__global__ void rope_tab(float* __restrict__ tab) {
    int i = blockIdx.x * 256 + threadIdx.x;   // 65536 = 2048 t x 32 d
    int t = i >> 5, d = i & 31;
    float invf = powf(10000.0f, -(float)d / 32.0f);
    float ang = (float)t * invf;
    tab[i] = cosf(ang);
    tab[i + 65536] = sinf(ang);
}

// ---------- fused QKV GEMM + RoPE + pack epilogue, 8 waves (512 thr) ----------
__global__ __launch_bounds__(512) void gemm_qkv(const u16* __restrict__ A,
                                                const u16* __restrict__ Bt,
                                                const float* __restrict__ tab,
                                                u16* __restrict__ qb,
                                                u16* __restrict__ kb,
                                                u16* __restrict__ vt,
                                                int M, int N, int K) {
    __shared__ u16 lA[128 * 64];
    __shared__ u16 lB[128 * 64];
    const int tid = threadIdx.x;
    const int wave = tid >> 6, lane = tid & 63;
    const int l15 = lane & 15, l4 = lane >> 4;
    const int nwg = gridDim.x * gridDim.y;
    const int orig = blockIdx.y * gridDim.x + blockIdx.x;
    const int swz = (orig & 7) * (nwg >> 3) + (orig >> 3);
    const int m0 = (swz / gridDim.x) * 128, n0 = (swz % gridDim.x) * 128;
    const int wm = (wave >> 1) * 32, wn = (wave & 1) * 64;
    f32x4 acc[2][4] = {};
    for (int k0 = 0; k0 < K; k0 += 64) {
#pragma unroll
        for (int it = 0; it < 2; ++it) {
            int cb = it * 512 + wave * 64;
            int c = cb + lane;
            int r = c >> 3, s = c & 7;
            int sd = ((s ^ (r & 7)) << 3);
            gload_lds16(A + (size_t)(m0 + r) * K + k0 + sd, &lA[(size_t)cb * 8]);
            gload_lds16(Bt + (size_t)(n0 + r) * K + k0 + sd, &lB[(size_t)cb * 8]);
        }
        __syncthreads();
#pragma unroll
        for (int kk = 0; kk < 2; ++kk) {
            bf16x8 af[2], bf[4];
#pragma unroll
            for (int mi = 0; mi < 2; ++mi) {
                int row = wm + mi * 16 + l15;
                af[mi] = *(const bf16x8*)(&lA[row * 64 + (((kk * 4 + l4) ^ (row & 7)) << 3)]);
            }
#pragma unroll
            for (int ni = 0; ni < 4; ++ni) {
                int row = wn + ni * 16 + l15;
                bf[ni] = *(const bf16x8*)(&lB[row * 64 + (((kk * 4 + l4) ^ (row & 7)) << 3)]);
            }
#pragma unroll
            for (int mi = 0; mi < 2; ++mi)
#pragma unroll
                for (int ni = 0; ni < 4; ++ni)
                    acc[mi][ni] = mfma16(af[mi], bf[ni], acc[mi][ni]);
        }
        __syncthreads();
    }
    // ---- fused epilogue ----
    const int colg = n0 + wn;
    const int region = colg >> 10;       // 0=q, 1=k, 2=v
    const int h = (colg & 1023) >> 6;
    if (region == 2) {
#pragma unroll
        for (int mi = 0; mi < 2; ++mi) {
            int t0 = m0 + wm + mi * 16 + l4 * 4;
            int b = t0 >> 11, tq0 = t0 & 2047;
#pragma unroll
            for (int ni = 0; ni < 4; ++ni) {
                int dcol = ni * 16 + l15;
                uint2 pk;
                pk.x = pack2(acc[mi][ni][0], acc[mi][ni][1]);
                pk.y = pack2(acc[mi][ni][2], acc[mi][ni][3]);
                *(uint2*)(vt + ((size_t)(b * 16 + h) * 64 + dcol) * 2048 + tq0) = pk;
            }
        }
    } else {
        const float sc = (region == 0) ? ROPE_SC : 1.0f;
        u16* dst = (region == 0) ? qb : kb;
#pragma unroll
        for (int mi = 0; mi < 2; ++mi)
#pragma unroll
            for (int i = 0; i < 4; ++i) {
                int t = m0 + wm + mi * 16 + l4 * 4 + i;
                int b = t >> 11, tq = t & 2047;
                const float* tcb = tab + tq * 32;
                const float* tsb = tab + 65536 + tq * 32;
                size_t base = ((size_t)(b * 16 + h) * 2048 + tq) * 64;
#pragma unroll
                for (int ni = 0; ni < 2; ++ni) {
                    int d32 = ni * 16 + l15;
                    float cs = tcb[d32], sn = tsb[d32];
                    float a = acc[mi][ni][i], bb = acc[mi][ni + 2][i];
                    dst[base + d32]      = f2bf((a * cs - bb * sn) * sc);
                    dst[base + d32 + 32] = f2bf((bb * cs + a * sn) * sc);
                }
            }
    }
}

// ---------- GEMM 128x64 tile (final proj), 8 waves: grid (N/64, M/128) ----------
__global__ __launch_bounds__(512) void gemm_bt_n64(const u16* __restrict__ A,
                                                   const u16* __restrict__ Bt,
                                                   float* __restrict__ C,
                                                   int M, int N, int K) {
    __shared__ u16 lA[128 * 64];
    __shared__ u16 lB[64 * 64];
    const int tid = threadIdx.x;
    const int wave = tid >> 6, lane = tid & 63;
    const int l15 = lane & 15, l4 = lane >> 4;
    const int nwg = gridDim.x * gridDim.y;
    const int orig = blockIdx.y * gridDim.x + blockIdx.x;
    const int swz = (orig & 7) * (nwg >> 3) + (orig >> 3);
    const int m0 = (swz / gridDim.x) * 128, n0 = (swz % gridDim.x) * 64;
    const int wm = (wave >> 1) * 32, wn = (wave & 1) * 32;
    f32x4 acc[2][2] = {};
    for (int k0 = 0; k0 < K; k0 += 64) {
#pragma unroll
        for (int it = 0; it < 2; ++it) {
            int cb = it * 512 + wave * 64;
            int c = cb + lane;
            int r = c >> 3, s = c & 7;
            int sd = ((s ^ (r & 7)) << 3);
            gload_lds16(A + (size_t)(m0 + r) * K + k0 + sd, &lA[(size_t)cb * 8]);
        }
        {
            int cb = wave * 64;
            int c = cb + lane;
            int r = c >> 3, s = c & 7;
            int sd = ((s ^ (r & 7)) << 3);
            gload_lds16(Bt + (size_t)(n0 + r) * K + k0 + sd, &lB[(size_t)cb * 8]);
        }
        __syncthreads();
#pragma unroll
        for (int kk = 0; kk < 2; ++kk) {
            bf16x8 af[2], bf[2];
#pragma unroll
            for (int mi = 0; mi < 2; ++mi) {
                int row = wm + mi * 16 + l15;
                af[mi] = *(const bf16x8*)(&lA[row * 64 + (((kk * 4 + l4) ^ (row & 7)) << 3)]);
            }
#pragma unroll
            for (int ni = 0; ni < 2; ++ni) {
                int row = wn + ni * 16 + l15;
                bf[ni] = *(const bf16x8*)(&lB[row * 64 + (((kk * 4 + l4) ^ (row & 7)) << 3)]);
            }
#pragma unroll
            for (int mi = 0; mi < 2; ++mi)
#pragma unroll
                for (int ni = 0; ni < 2; ++ni)
                    acc[mi][ni] = mfma16(af[mi], bf[ni], acc[mi][ni]);
        }
        __syncthreads();
    }
#pragma unroll
    for (int mi = 0; mi < 2; ++mi)
#pragma unroll
        for (int ni = 0; ni < 2; ++ni)
#pragma unroll
            for (int i = 0; i < 4; ++i) {
                int r = m0 + wm + mi * 16 + l4 * 4 + i;
                int cc = n0 + wn + ni * 16 + l15;
                C[(size_t)r * N + cc] = acc[mi][ni][i];
            }
}

// ---------- causal flash attention v14: flash10 + exact-skip rescale + mfma row-sum ----------
// Structure (grid 1024x256, XCD map, K/V LDS dbuf, pi-scramble QK, zero-shuffle P->PV)
// VERBATIM from R10-proven flash10. Changes:
//  (a) rescale branch skipped when !__any(m > mrun) - corr==1 exactly, identity skip.
//  (b) row-sum via lacc = mfma(af, ones, lacc) in O-layout (replaces rs adds + shuffles).
__global__ __launch_bounds__(256, 4) void flash14(const u16* __restrict__ qb,
                                                  const u16* __restrict__ kb,
                                                  const u16* __restrict__ vt,
                                                  u16* __restrict__ ao) {
    __shared__ u16 lK[2][64 * 64];   // [kv][d], f_K-XOR-swizzled 16B slots
    __shared__ u16 lV[2][64 * 64];   // [d][kv], row&7-XOR-swizzled 16B slots
    const int orig = blockIdx.x;
    const int xcd = orig & 7, p = orig >> 3;
    const int cup = p & 31, layer = p >> 5;
    const int bh = xcd * 4 + layer;
    const int qt = (layer & 1) ? cup : 31 - cup;
    const int b = bh >> 4, h = bh & 15;
    const int tid = threadIdx.x;
    const int wave = tid >> 6, lane = tid & 63;
    const int l15 = lane & 15, l4 = lane >> 4;
    const u16* qptr = qb + (size_t)bh * 2048 * 64;
    const u16* kptr = kb + (size_t)bh * 2048 * 64;
    const u16* vptr = vt + (size_t)bh * 64 * 2048;

    const int qrow = qt * 64 + wave * 16 + l15;
    bf16x8 q0 = *(const bf16x8*)(qptr + (size_t)qrow * 64 + l4 * 8);
    bf16x8 q1 = *(const bf16x8*)(qptr + (size_t)qrow * 64 + 32 + l4 * 8);

    f32x4 O[4] = {};
    f32x4 lacc = {};
    float mrun = -INFINITY;

    bf16x8 onesf;
#pragma unroll
    for (int j = 0; j < 8; ++j) onesf[j] = (short)0x3F80;   // bf16 1.0

    int idxO[4];
#pragma unroll
    for (int i = 0; i < 4; ++i) idxO[i] = (lane & 48) | (l4 * 4 + i);

    const int r0q = ((l15 >> 2) << 3) | (l15 & 3);   // pi base row

    auto stage = [&](int buf, int kv0) {
#pragma unroll
        for (int it = 0; it < 2; ++it) {
            int cb = wave * 64 + it * 256;       // wave-uniform chunk base
            int c = cb + lane;
            int r = c >> 3, s = c & 7;
            int fK = (r & 3) | ((r >> 1) & 4);
            gload_lds16(kptr + (size_t)(kv0 + r) * 64 + ((s ^ fK) << 3), &lK[buf][cb * 8]);
            gload_lds16(vptr + (size_t)r * 2048 + kv0 + ((s ^ (r & 7)) << 3), &lV[buf][cb * 8]);
        }
    };
    auto ldK = [&](int buf, int row, int slot) -> bf16x8 {
        int f = (row & 3) | ((row >> 1) & 4);
        return *(const bf16x8*)(&lK[buf][row * 64 + ((slot ^ f) << 3)]);
    };
    auto ldV = [&](int buf, int row, int slot) -> bf16x8 {
        return *(const bf16x8*)(&lV[buf][row * 64 + ((slot ^ (row & 7)) << 3)]);
    };

    // softmax + pack-to-A-frag; p2[m][i] at kv = kv0 + 32(m>>1) + 8*l4 + 4(m&1) + i
    auto smpack = [&](f32x4 S[4], float& mr, f32x4& la, f32x4 Ov[4],
                      bf16x8 af[2], bool diag, int kv0, int qr) {
        float p2[4][4];
#pragma unroll
        for (int m = 0; m < 4; ++m)
#pragma unroll
            for (int i = 0; i < 4; ++i) {
                float s = S[m][i];
                if (diag && (kv0 + ((m >> 1) << 5) + (l4 << 3) + ((m & 1) << 2) + i > qr))
                    s = -INFINITY;
                p2[m][i] = s;
            }
        float m = p2[0][0];
#pragma unroll
        for (int c = 0; c < 4; ++c)
#pragma unroll
            for (int i = 0; i < 4; ++i) m = fmaxf(m, p2[c][i]);
        m = fmaxf(m, __shfl_xor(m, 16));
        m = fmaxf(m, __shfl_xor(m, 32));
        if (__any(m > mr)) {                      // max grew: rescale (else corr==1 exactly)
            float mnew = fmaxf(mr, m);
            float corr = __builtin_amdgcn_exp2f(mr - mnew);
            mr = mnew;
            f32x4 cfv;
#pragma unroll
            for (int i = 0; i < 4; ++i) cfv[i] = __shfl(corr, idxO[i]);
            Ov[0] *= cfv; Ov[1] *= cfv; Ov[2] *= cfv; Ov[3] *= cfv;
            la *= cfv;
        }
#pragma unroll
        for (int c = 0; c < 4; ++c)
#pragma unroll
            for (int i = 0; i < 4; ++i)
                p2[c][i] = __builtin_amdgcn_exp2f(p2[c][i] - mr);   // <= 1
        unsigned w[4][2];
#pragma unroll
        for (int c = 0; c < 4; ++c) {
            asm("v_cvt_pk_bf16_f32 %0, %1, %2" : "=v"(w[c][0]) : "v"(p2[c][0]), "v"(p2[c][1]));
            asm("v_cvt_pk_bf16_f32 %0, %1, %2" : "=v"(w[c][1]) : "v"(p2[c][2]), "v"(p2[c][3]));
        }
#pragma unroll
        for (int ks = 0; ks < 2; ++ks) {
            union { unsigned u[4]; bf16x8 v; } cvt;
            cvt.u[0] = w[2 * ks][0];
            cvt.u[1] = w[2 * ks][1];
            cvt.u[2] = w[2 * ks + 1][0];
            cvt.u[3] = w[2 * ks + 1][1];
            af[ks] = cvt.v;
        }
        // row-sum via MFMA: la[i] += sum_kv P[q'=l4*4+i][kv] - O-layout, bf16-consistent
        la = mfma16(af[0], onesf, la);
        la = mfma16(af[1], onesf, la);
    };

    stage(0, 0);
    for (int kvb = 0; kvb <= qt; ++kvb) {
        const int cur = kvb & 1;
        const int kv0 = kvb * 64;
        if (kvb < qt) {
            stage(cur ^ 1, kv0 + 64);
            asm volatile("s_waitcnt vmcnt(4)" ::: "memory");
        } else {
            asm volatile("s_waitcnt vmcnt(0)" ::: "memory");
        }
        __builtin_amdgcn_s_barrier();
        __builtin_amdgcn_sched_barrier(0);

        // QK^T swapped with pi-scrambled A-rows
        f32x4 S[4] = {};
#pragma unroll
        for (int mm = 0; mm < 4; ++mm) {
            int row = r0q + ((mm >> 1) << 5) + ((mm & 1) << 2);
            bf16x8 kf0 = ldK(cur, row, l4);
            bf16x8 kf1 = ldK(cur, row, 4 + l4);
            S[mm] = mfma16(kf0, q0, S[mm]);
            S[mm] = mfma16(kf1, q1, S[mm]);
        }
        bf16x8 af[2];
        smpack(S, mrun, lacc, O, af, kvb == qt, kv0, qrow);
#pragma unroll
        for (int ks = 0; ks < 2; ++ks)
#pragma unroll
            for (int c2 = 0; c2 < 4; ++c2) {
                bf16x8 vf = ldV(cur, c2 * 16 + l15, ks * 4 + l4);
                O[c2] = mfma16(af[ks], vf, O[c2]);
            }
        __builtin_amdgcn_s_barrier();   // protect buffer overwrite by next stage
    }

    // epilogue: O rows are q'=l4*4+i, cols d=c2*16+l15; lacc already in O-layout
#pragma unroll
    for (int i = 0; i < 4; ++i) {
        float rcp = 1.f / lacc[i];
        int qg = qt * 64 + wave * 16 + l4 * 4 + i;
#pragma unroll
        for (int c2 = 0; c2 < 4; ++c2)
            ao[(size_t)(b * 2048 + qg) * 1024 + h * 64 + c2 * 16 + l15] = f2bf(O[c2][i] * rcp);
    }
}

// ---------- launch ----------
extern "C" void kernel_launch(void* const* d_in, const int* in_sizes, int n_in,
                              void* d_out, int out_size, void* d_ws, size_t ws_size,
                              hipStream_t stream) {
    const float* x    = (const float*)d_in[0];   // (2,2048,1024)
    const float* Wqkv = (const float*)d_in[1];   // (1024,3072)
    const float* Wout = (const float*)d_in[2];   // (1024,1024)
    float* out = (float*)d_out;                  // (2,2048,1024)
    char* ws = (char*)d_ws;

    u16*   xb  = (u16*)(ws + 0);            // 8 MB  (4096x1024 bf16)
    u16*   Wtq = (u16*)(ws + 8388608);      // 6 MB  (3072x1024 bf16)
    u16*   Wto = (u16*)(ws + 14680064);     // 2 MB  (1024x1024 bf16)
    u16*   qb  = (u16*)(ws + 67108864);     // 8 MB  (B,H,T,Dh bf16, pre-scaled)
    u16*   kb  = (u16*)(ws + 75497472);     // 8 MB
    u16*   vt  = (u16*)(ws + 83886080);     // 8 MB  (B,H,Dh,T bf16)
    float* tab = (float*)(ws + 92274688);   // 512 KB sin/cos table
    u16*   ao  = (u16*)(ws + 0);            // reuse xb region (gemm_qkv done by then)

    cvt_bf16<<<dim3(4096), dim3(256), 0, stream>>>(x, xb);
    transpose_cvt<<<dim3(96, 32), dim3(256), 0, stream>>>(Wqkv, Wtq, 1024, 3072);
    transpose_cvt<<<dim3(32, 32), dim3(256), 0, stream>>>(Wout, Wto, 1024, 1024);
    rope_tab<<<dim3(256), dim3(256), 0, stream>>>(tab);
    gemm_qkv<<<dim3(24, 32), dim3(512), 0, stream>>>(xb, Wtq, tab, qb, kb, vt, 4096, 3072, 1024);
    flash14<<<dim3(1024), dim3(256), 0, stream>>>(qb, kb, vt, ao);
    gemm_bt_n64<<<dim3(16, 32), dim3(512), 0, stream>>>(ao, Wto, out, 4096, 1024, 1024);
}